// Round 4
// baseline (163.142 us; speedup 1.0000x reference)
//
#include <hip/hip_runtime.h>

// ImplicitNetOC: u = clip(-pB) ; pB = relu(relu([x,t]W1+b1)W2+b2) @ (W3@Bmat) + b3@Bmat
// R4: TRANSPOSED orientation — batch on the MFMA N side. H^T = W^T X^T chains with
// wide LDS ops on both sides (b64 stores / b128 reads); weights live in registers
// as A-fragments, loaded once per block from global. Single kernel launch.

typedef __bf16 bf16;
typedef __bf16 bf16x8 __attribute__((ext_vector_type(8)));
typedef __bf16 bf16x4 __attribute__((ext_vector_type(4)));
typedef float  f32x4  __attribute__((ext_vector_type(4)));

#define HID    256
#define SDIM   64
#define CDIM   16
#define BM     128
#define GRID   256      // == CU count; 4 tiles of 128 rows per block
#define ITERS  4        // 131072 / (BM*GRID)
#define LDH    264      // bf16 stride for sH1/sH2 (528 B; 33 granules of 8 bf16)
#define LDX    72       // bf16 stride for sX (144 B)

#define MFMA(a, b, c) __builtin_amdgcn_mfma_f32_16x16x32_bf16(a, b, c, 0, 0, 0)

// swizzled index into sH* (bf16 units): element (batch row, hidden h).
// granule = 8 bf16 = 16 B; XOR by row&7 spreads banks (all accesses have row%16==lane&15).
__device__ __forceinline__ int sh_idx(int row, int h) {
  const int g = (h >> 3) ^ (row & 7);
  return row * LDH + g * 8 + (h & 7);
}

__global__ __launch_bounds__(512, 2)
void oc_main(const float* __restrict__ x,  const float* __restrict__ t,
             const float* __restrict__ W1, const float* __restrict__ b1,
             const float* __restrict__ W2, const float* __restrict__ b2,
             const float* __restrict__ W3, const float* __restrict__ b3,
             const float* __restrict__ Bmat, float* __restrict__ out) {
  __shared__ bf16 sH1[BM * LDH];   // H1^T-ish store [batch][hidden]; reused as H2-lo
  __shared__ bf16 sH2[BM * LDH];   // H2-hi
  __shared__ bf16 sX [BM * LDX];   // staged X [batch][k]
  const int tid  = threadIdx.x;
  const int wave = tid >> 6, lane = tid & 63;
  const int q    = lane >> 4, l = lane & 15;

  // ---- stage helper: X tile (fp32 global -> bf16 LDS, native [batch][k]) ----
  auto stage = [&](int tile) {
    const float* xp = x + (size_t)tile * BM * SDIM;
#pragma unroll
    for (int i = 0; i < 4; ++i) {
      const int e = i * 512 + tid;            // 2048 float4 = 128 x 64 floats
      const int r = e >> 4, k4 = (e & 15) * 4;
      const float4 v = *(const float4*)(xp + r * SDIM + k4);
      bf16x4 w = {(bf16)v.x, (bf16)v.y, (bf16)v.z, (bf16)v.w};
      *(bf16x4*)(&sX[r * LDX + k4]) = w;
    }
  };

  // ---- phase 0: cooperative W3B^T = (W3 @ Bmat)^T fragment build in sH1 scratch,
  //      concurrent with staging tile0's X ----
  {
    const int n1 = tid >> 1;            // hidden index 0..255
    const int cb = (tid & 1) * 8;       // control cols [cb, cb+8)
    float aw[8];
#pragma unroll
    for (int i = 0; i < 8; ++i) aw[i] = 0.f;
    for (int m = 0; m < SDIM; ++m) {
      const float w = W3[n1 * SDIM + m];
      const float4 bA = *(const float4*)(&Bmat[m * CDIM + cb]);
      const float4 bB = *(const float4*)(&Bmat[m * CDIM + cb + 4]);
      aw[0] = fmaf(w, bA.x, aw[0]); aw[1] = fmaf(w, bA.y, aw[1]);
      aw[2] = fmaf(w, bA.z, aw[2]); aw[3] = fmaf(w, bA.w, aw[3]);
      aw[4] = fmaf(w, bB.x, aw[4]); aw[5] = fmaf(w, bB.y, aw[5]);
      aw[6] = fmaf(w, bB.z, aw[6]); aw[7] = fmaf(w, bB.w, aw[7]);
    }
    // A-frag layout for W3B^T: frag kt, lane (qq*16 + c), elem jj  <-  n1 = 32kt+8qq+jj
    const int kt = n1 >> 5, qq = (n1 >> 3) & 3, jj = n1 & 7;
#pragma unroll
    for (int ci = 0; ci < 8; ++ci)
      sH1[(kt * 64 + qq * 16 + cb + ci) * 8 + jj] = (bf16)aw[ci];
  }
  stage(blockIdx.x);
  __syncthreads();

  // ---- per-wave register A-fragments + biases ----
  bf16x8 W3t[8];
#pragma unroll
  for (int kt = 0; kt < 8; ++kt)
    W3t[kt] = *(const bf16x8*)(&sH1[(kt * 64 + lane) * 8]);

  // W^T A-frags: A[m=hidden][k] ; lane&15 = hidden-in-tile, k = q*8+j
  bf16x8 W1t[2][2], W2t[8][2];
#pragma unroll
  for (int kt = 0; kt < 2; ++kt)
#pragma unroll
    for (int mt = 0; mt < 2; ++mt) {
      bf16x8 v;
#pragma unroll
      for (int j = 0; j < 8; ++j)
        v[j] = (bf16)W1[(32 * kt + 8 * q + j) * HID + 32 * wave + 16 * mt + l];
      W1t[kt][mt] = v;
    }
#pragma unroll
  for (int kt = 0; kt < 8; ++kt)
#pragma unroll
    for (int mt = 0; mt < 2; ++mt) {
      bf16x8 v;
#pragma unroll
      for (int j = 0; j < 8; ++j)
        v[j] = (bf16)W2[(32 * kt + 8 * q + j) * HID + 32 * wave + 16 * mt + l];
      W2t[kt][mt] = v;
    }

  const float tt = t[0];
  f32x4 b1e[2], b2e[2];
#pragma unroll
  for (int mt = 0; mt < 2; ++mt)
#pragma unroll
    for (int r = 0; r < 4; ++r) {
      const int h = 32 * wave + 16 * mt + 4 * q + r;
      b1e[mt][r] = b1[h] + tt * W1[SDIM * HID + h];   // fold t-column
      b2e[mt][r] = b2[h];
    }
  f32x4 b3t = (f32x4){0.f, 0.f, 0.f, 0.f};
  for (int m = 0; m < SDIM; ++m) {
    const float bm = b3[m];
    const float4 v = *(const float4*)(&Bmat[m * CDIM + 4 * q]);
    b3t[0] = fmaf(bm, v.x, b3t[0]); b3t[1] = fmaf(bm, v.y, b3t[1]);
    b3t[2] = fmaf(bm, v.z, b3t[2]); b3t[3] = fmaf(bm, v.w, b3t[3]);
  }
  __syncthreads();   // W3t frags consumed; sH1 free for L1 stores

  f32x4 acc[2][8];

  for (int it = 0; it < ITERS; ++it) {
    const int tile = blockIdx.x + it * GRID;

    // ---- layer 1: H1^T = relu(W1^T X^T + b1)  (M=hidden split 32/wave, N=batch) ----
#pragma unroll
    for (int mt = 0; mt < 2; ++mt)
#pragma unroll
      for (int nt = 0; nt < 8; ++nt) acc[mt][nt] = (f32x4){0.f, 0.f, 0.f, 0.f};
#pragma unroll
    for (int kt = 0; kt < 2; ++kt)
#pragma unroll
      for (int nt = 0; nt < 8; ++nt) {
        const bf16x8 b = *(const bf16x8*)(&sX[(16 * nt + l) * LDX + 32 * kt + 8 * q]);
        acc[0][nt] = MFMA(W1t[kt][0], b, acc[0][nt]);
        acc[1][nt] = MFMA(W1t[kt][1], b, acc[1][nt]);
      }
#pragma unroll
    for (int mt = 0; mt < 2; ++mt) {
      const int h0 = 32 * wave + 16 * mt + 4 * q;
#pragma unroll
      for (int nt = 0; nt < 8; ++nt) {
        bf16x4 v;
#pragma unroll
        for (int r = 0; r < 4; ++r) v[r] = (bf16)fmaxf(acc[mt][nt][r] + b1e[mt][r], 0.f);
        *(bf16x4*)(&sH1[sh_idx(16 * nt + l, h0)]) = v;
      }
    }
    __syncthreads();   // A: H1 visible; sX readable until restage

    // ---- layer 2: H2^T = relu(W2^T H1^T + b2)  K=256 ----
#pragma unroll
    for (int mt = 0; mt < 2; ++mt)
#pragma unroll
      for (int nt = 0; nt < 8; ++nt) acc[mt][nt] = (f32x4){0.f, 0.f, 0.f, 0.f};
#pragma unroll
    for (int kt = 0; kt < 8; ++kt)
#pragma unroll
      for (int nt = 0; nt < 8; ++nt) {
        const bf16x8 b = *(const bf16x8*)(&sH1[sh_idx(16 * nt + l, 32 * kt + 8 * q)]);
        acc[0][nt] = MFMA(W2t[kt][0], b, acc[0][nt]);
        acc[1][nt] = MFMA(W2t[kt][1], b, acc[1][nt]);
      }
    if (it + 1 < ITERS) stage(tile + GRID);   // prefetch next X into sX
    __syncthreads();   // B: sH1 reads done -> overwritable as H2-lo; sX restaged

    // ---- H2 writeback: hi (sH2) + lo residual (sH1), b64 each ----
#pragma unroll
    for (int mt = 0; mt < 2; ++mt) {
      const int h0 = 32 * wave + 16 * mt + 4 * q;
#pragma unroll
      for (int nt = 0; nt < 8; ++nt) {
        bf16x4 hi, lo;
#pragma unroll
        for (int r = 0; r < 4; ++r) {
          const float v = fmaxf(acc[mt][nt][r] + b2e[mt][r], 0.f);
          const bf16 h = (bf16)v;
          hi[r] = h;
          lo[r] = (bf16)(v - (float)h);
        }
        const int idx = sh_idx(16 * nt + l, h0);
        *(bf16x4*)(&sH2[idx]) = hi;
        *(bf16x4*)(&sH1[idx]) = lo;
      }
    }
    __syncthreads();   // C: H2 hi/lo visible

    // ---- layer 3: u^T = clip(-(W3B^T (H2hi+H2lo)^T + b3B))  N-split: wave -> 16 batch ----
    f32x4 a3 = (f32x4){0.f, 0.f, 0.f, 0.f};
#pragma unroll
    for (int kt = 0; kt < 8; ++kt) {
      const int idx = sh_idx(16 * wave + l, 32 * kt + 8 * q);
      const bf16x8 bh = *(const bf16x8*)(&sH2[idx]);
      const bf16x8 bl = *(const bf16x8*)(&sH1[idx]);
      a3 = MFMA(W3t[kt], bh, a3);
      a3 = MFMA(W3t[kt], bl, a3);
    }
    f32x4 o;
#pragma unroll
    for (int r = 0; r < 4; ++r)
      o[r] = fminf(fmaxf(-(a3[r] + b3t[r]), -1.f), 1.f);
    *(float4*)(&out[((size_t)tile * BM + 16 * wave + l) * CDIM + 4 * q]) = *(float4*)&o;

    __syncthreads();   // D: L3 reads done before next L1 overwrites sH1
  }
}

extern "C" void kernel_launch(void* const* d_in, const int* in_sizes, int n_in,
                              void* d_out, int out_size, void* d_ws, size_t ws_size,
                              hipStream_t stream) {
  const float* x    = (const float*)d_in[0];
  const float* t    = (const float*)d_in[1];
  const float* W1   = (const float*)d_in[2];
  const float* b1   = (const float*)d_in[3];
  const float* W2   = (const float*)d_in[4];
  const float* b2   = (const float*)d_in[5];
  const float* W3   = (const float*)d_in[6];
  const float* b3   = (const float*)d_in[7];
  const float* Bmat = (const float*)d_in[8];
  float* out = (float*)d_out;
  (void)d_ws; (void)ws_size;

  hipLaunchKernelGGL(oc_main, dim3(GRID), dim3(512), 0, stream,
                     x, t, W1, b1, W2, b2, W3, b3, Bmat, out);
}

// Round 5
// 129.078 us; speedup vs baseline: 1.2639x; 1.2639x over previous
//
#include <hip/hip_runtime.h>

// ImplicitNetOC: u = clip(-pB) ; pB = relu(relu([x,t]W1+b1)W2+b2) @ (W3@Bmat) + b3@Bmat
// R5: R4 transposed structure (batch on MFMA N side, weights register-resident as
// A-frags, single launch) with the XOR bank-swizzle REMOVED: plain row*264+h layout
// is already conflict-minimal (stride 132 dwords == 4 mod 32 banks spreads rows;
// the XOR composed with that additive term was a non-permutation -> 4x conflicts).

typedef __bf16 bf16;
typedef __bf16 bf16x8 __attribute__((ext_vector_type(8)));
typedef __bf16 bf16x4 __attribute__((ext_vector_type(4)));
typedef float  f32x4  __attribute__((ext_vector_type(4)));

#define HID    256
#define SDIM   64
#define CDIM   16
#define BM     128
#define GRID   256      // == CU count; 4 tiles of 128 rows per block
#define ITERS  4        // 131072 / (BM*GRID)
#define LDH    264      // bf16 stride for sH1/sH2 (528 B; 132 dwords == 4 mod 32 banks)
#define LDX    72       // bf16 stride for sX (144 B; 36 dwords == 4 mod 32 banks)

#define MFMA(a, b, c) __builtin_amdgcn_mfma_f32_16x16x32_bf16(a, b, c, 0, 0, 0)

// plain layout: the additive row stride IS the bank spread; do not XOR on top.
__device__ __forceinline__ int sh_idx(int row, int h) { return row * LDH + h; }

__global__ __launch_bounds__(512, 2)
void oc_main(const float* __restrict__ x,  const float* __restrict__ t,
             const float* __restrict__ W1, const float* __restrict__ b1,
             const float* __restrict__ W2, const float* __restrict__ b2,
             const float* __restrict__ W3, const float* __restrict__ b3,
             const float* __restrict__ Bmat, float* __restrict__ out) {
  __shared__ bf16 sH1[BM * LDH];   // H1 [batch][hidden]; reused as H2-lo
  __shared__ bf16 sH2[BM * LDH];   // H2-hi
  __shared__ bf16 sX [BM * LDX];   // staged X [batch][k]
  const int tid  = threadIdx.x;
  const int wave = tid >> 6, lane = tid & 63;
  const int q    = lane >> 4, l = lane & 15;

  // ---- stage helper: X tile (fp32 global -> bf16 LDS, [batch][k]) ----
  auto stage = [&](int tile) {
    const float* xp = x + (size_t)tile * BM * SDIM;
#pragma unroll
    for (int i = 0; i < 4; ++i) {
      const int e = i * 512 + tid;            // 2048 float4 = 128 x 64 floats
      const int r = e >> 4, k4 = (e & 15) * 4;
      const float4 v = *(const float4*)(xp + r * SDIM + k4);
      bf16x4 w = {(bf16)v.x, (bf16)v.y, (bf16)v.z, (bf16)v.w};
      *(bf16x4*)(&sX[r * LDX + k4]) = w;
    }
  };

  // ---- phase 0: cooperative W3B^T = (W3 @ Bmat)^T A-frags in sH1 scratch ----
  {
    const int n1 = tid >> 1;            // hidden index 0..255
    const int cb = (tid & 1) * 8;       // control cols [cb, cb+8)
    float aw[8];
#pragma unroll
    for (int i = 0; i < 8; ++i) aw[i] = 0.f;
    for (int m = 0; m < SDIM; ++m) {
      const float w = W3[n1 * SDIM + m];
      const float4 bA = *(const float4*)(&Bmat[m * CDIM + cb]);
      const float4 bB = *(const float4*)(&Bmat[m * CDIM + cb + 4]);
      aw[0] = fmaf(w, bA.x, aw[0]); aw[1] = fmaf(w, bA.y, aw[1]);
      aw[2] = fmaf(w, bA.z, aw[2]); aw[3] = fmaf(w, bA.w, aw[3]);
      aw[4] = fmaf(w, bB.x, aw[4]); aw[5] = fmaf(w, bB.y, aw[5]);
      aw[6] = fmaf(w, bB.z, aw[6]); aw[7] = fmaf(w, bB.w, aw[7]);
    }
    // A-frag: frag kt, lane (qq*16 + c), elem jj  <-  n1 = 32kt+8qq+jj
    const int kt = n1 >> 5, qq = (n1 >> 3) & 3, jj = n1 & 7;
#pragma unroll
    for (int ci = 0; ci < 8; ++ci)
      sH1[(kt * 64 + qq * 16 + cb + ci) * 8 + jj] = (bf16)aw[ci];
  }
  stage(blockIdx.x);
  __syncthreads();

  // ---- per-wave register A-fragments + biases ----
  bf16x8 W3t[8];
#pragma unroll
  for (int kt = 0; kt < 8; ++kt)
    W3t[kt] = *(const bf16x8*)(&sH1[(kt * 64 + lane) * 8]);

  // W^T A-frags: A[m=hidden][k] ; lane&15 = hidden-in-tile, k = q*8+j
  bf16x8 W1t[2][2], W2t[8][2];
#pragma unroll
  for (int kt = 0; kt < 2; ++kt)
#pragma unroll
    for (int mt = 0; mt < 2; ++mt) {
      bf16x8 v;
#pragma unroll
      for (int j = 0; j < 8; ++j)
        v[j] = (bf16)W1[(32 * kt + 8 * q + j) * HID + 32 * wave + 16 * mt + l];
      W1t[kt][mt] = v;
    }
#pragma unroll
  for (int kt = 0; kt < 8; ++kt)
#pragma unroll
    for (int mt = 0; mt < 2; ++mt) {
      bf16x8 v;
#pragma unroll
      for (int j = 0; j < 8; ++j)
        v[j] = (bf16)W2[(32 * kt + 8 * q + j) * HID + 32 * wave + 16 * mt + l];
      W2t[kt][mt] = v;
    }

  const float tt = t[0];
  f32x4 b1e[2], b2e[2];
#pragma unroll
  for (int mt = 0; mt < 2; ++mt)
#pragma unroll
    for (int r = 0; r < 4; ++r) {
      const int h = 32 * wave + 16 * mt + 4 * q + r;
      b1e[mt][r] = b1[h] + tt * W1[SDIM * HID + h];   // fold t-column
      b2e[mt][r] = b2[h];
    }
  f32x4 b3t = (f32x4){0.f, 0.f, 0.f, 0.f};
  for (int m = 0; m < SDIM; ++m) {
    const float bm = b3[m];
    const float4 v = *(const float4*)(&Bmat[m * CDIM + 4 * q]);
    b3t[0] = fmaf(bm, v.x, b3t[0]); b3t[1] = fmaf(bm, v.y, b3t[1]);
    b3t[2] = fmaf(bm, v.z, b3t[2]); b3t[3] = fmaf(bm, v.w, b3t[3]);
  }
  __syncthreads();   // W3t frags consumed; sH1 free for L1 stores

  f32x4 acc[2][8];

  for (int it = 0; it < ITERS; ++it) {
    const int tile = blockIdx.x + it * GRID;

    // ---- layer 1: H1^T = relu(W1^T X^T + b1)  (M=hidden 32/wave, N=batch 128) ----
#pragma unroll
    for (int mt = 0; mt < 2; ++mt)
#pragma unroll
      for (int nt = 0; nt < 8; ++nt) acc[mt][nt] = (f32x4){0.f, 0.f, 0.f, 0.f};
#pragma unroll
    for (int kt = 0; kt < 2; ++kt)
#pragma unroll
      for (int nt = 0; nt < 8; ++nt) {
        const bf16x8 b = *(const bf16x8*)(&sX[(16 * nt + l) * LDX + 32 * kt + 8 * q]);
        acc[0][nt] = MFMA(W1t[kt][0], b, acc[0][nt]);
        acc[1][nt] = MFMA(W1t[kt][1], b, acc[1][nt]);
      }
#pragma unroll
    for (int mt = 0; mt < 2; ++mt) {
      const int h0 = 32 * wave + 16 * mt + 4 * q;
#pragma unroll
      for (int nt = 0; nt < 8; ++nt) {
        bf16x4 v;
#pragma unroll
        for (int r = 0; r < 4; ++r) v[r] = (bf16)fmaxf(acc[mt][nt][r] + b1e[mt][r], 0.f);
        *(bf16x4*)(&sH1[sh_idx(16 * nt + l, h0)]) = v;
      }
    }
    __syncthreads();   // A: H1 visible; all sX reads done

    // ---- layer 2: H2^T = relu(W2^T H1^T + b2)  K=256 ----
#pragma unroll
    for (int mt = 0; mt < 2; ++mt)
#pragma unroll
      for (int nt = 0; nt < 8; ++nt) acc[mt][nt] = (f32x4){0.f, 0.f, 0.f, 0.f};
#pragma unroll
    for (int kt = 0; kt < 8; ++kt)
#pragma unroll
      for (int nt = 0; nt < 8; ++nt) {
        const bf16x8 b = *(const bf16x8*)(&sH1[sh_idx(16 * nt + l, 32 * kt + 8 * q)]);
        acc[0][nt] = MFMA(W2t[kt][0], b, acc[0][nt]);
        acc[1][nt] = MFMA(W2t[kt][1], b, acc[1][nt]);
      }
    if (it + 1 < ITERS) stage(tile + GRID);   // prefetch next X into sX
    __syncthreads();   // B: sH1 reads done -> overwritable as H2-lo

    // ---- H2 writeback: hi (sH2) + lo residual (sH1), b64 each ----
#pragma unroll
    for (int mt = 0; mt < 2; ++mt) {
      const int h0 = 32 * wave + 16 * mt + 4 * q;
#pragma unroll
      for (int nt = 0; nt < 8; ++nt) {
        bf16x4 hi, lo;
#pragma unroll
        for (int r = 0; r < 4; ++r) {
          const float v = fmaxf(acc[mt][nt][r] + b2e[mt][r], 0.f);
          const bf16 h = (bf16)v;
          hi[r] = h;
          lo[r] = (bf16)(v - (float)h);
        }
        const int idx = sh_idx(16 * nt + l, h0);
        *(bf16x4*)(&sH2[idx]) = hi;
        *(bf16x4*)(&sH1[idx]) = lo;
      }
    }
    __syncthreads();   // C: H2 hi/lo visible

    // ---- layer 3: u^T = clip(-(W3B^T (H2hi+H2lo) + b3B))  wave -> 16 batch rows ----
    f32x4 a3 = (f32x4){0.f, 0.f, 0.f, 0.f};
#pragma unroll
    for (int kt = 0; kt < 8; ++kt) {
      const int idx = sh_idx(16 * wave + l, 32 * kt + 8 * q);
      const bf16x8 bh = *(const bf16x8*)(&sH2[idx]);
      const bf16x8 bl = *(const bf16x8*)(&sH1[idx]);
      a3 = MFMA(W3t[kt], bh, a3);
      a3 = MFMA(W3t[kt], bl, a3);
    }
    f32x4 o;
#pragma unroll
    for (int r = 0; r < 4; ++r)
      o[r] = fminf(fmaxf(-(a3[r] + b3t[r]), -1.f), 1.f);
    *(float4*)(&out[((size_t)tile * BM + 16 * wave + l) * CDIM + 4 * q]) = *(float4*)&o;

    __syncthreads();   // D: L3 reads done before next L1 overwrites sH1
  }
}

extern "C" void kernel_launch(void* const* d_in, const int* in_sizes, int n_in,
                              void* d_out, int out_size, void* d_ws, size_t ws_size,
                              hipStream_t stream) {
  const float* x    = (const float*)d_in[0];
  const float* t    = (const float*)d_in[1];
  const float* W1   = (const float*)d_in[2];
  const float* b1   = (const float*)d_in[3];
  const float* W2   = (const float*)d_in[4];
  const float* b2   = (const float*)d_in[5];
  const float* W3   = (const float*)d_in[6];
  const float* b3   = (const float*)d_in[7];
  const float* Bmat = (const float*)d_in[8];
  float* out = (float*)d_out;
  (void)d_ws; (void)ws_size;

  hipLaunchKernelGGL(oc_main, dim3(GRID), dim3(512), 0, stream,
                     x, t, W1, b1, W2, b2, W3, b3, Bmat, out);
}